// Round 8
// baseline (323.028 us; speedup 1.0000x reference)
//
#include <hip/hip_runtime.h>

#define HC 60
#define WC 80
#define NPTS 4800        // HC*WC
#define DD 256
#define MP 4864          // rows padded to 38*128
#define NB 2

typedef __attribute__((ext_vector_type(8))) short short8;
typedef __attribute__((ext_vector_type(4))) float f32x4;
typedef __bf16 bf16x8 __attribute__((ext_vector_type(8)));

__device__ __forceinline__ float bf2f(unsigned short u) {
  unsigned x = ((unsigned)u) << 16;
  return __builtin_bit_cast(float, x);
}
__device__ __forceinline__ unsigned short f2bf(float f) {
  unsigned u = __builtin_bit_cast(unsigned, f);
  u += 0x7fffu + ((u >> 16) & 1u);
  return (unsigned short)(u >> 16);
}

// ------- init: zero accumulators + warped coordinates (fused, 38x256) -------
__global__ void init_kernel(float* __restrict__ C2, float* __restrict__ R2,
                            float* __restrict__ normsum, float* __restrict__ out,
                            const float* __restrict__ Hinv, float* __restrict__ wc) {
  int idx = blockIdx.x * 256 + threadIdx.x;
  if (idx < NB) normsum[idx] = 0.f;
  if (idx == 0) out[0] = 0.f;
  if (idx >= NB * NPTS) return;
  C2[idx] = 0.f; R2[idx] = 0.f;
  int b = idx / NPTS, r = idx % NPTS;
  int i = r / WC, j = r % WC;
  float y = i * 8.f + 4.f, x = j * 8.f + 4.f;
  const float* h = Hinv + b * 9;
  float q0 = h[0] * x + h[1] * y + h[2];
  float q1 = h[3] * x + h[4] * y + h[5];
  float z  = h[6] * x + h[7] * y + h[8];
  if (fabsf(z) <= 1e-8f) z = 1e-8f;
  wc[idx * 2 + 0] = q1 / z;   // wy
  wc[idx * 2 + 1] = q0 / z;   // wx
}

// ---------------- per-row l2-normalize + bf16 cast (pad rows -> 0) ----------
__global__ void prep_kernel(const float* __restrict__ din, const float* __restrict__ win,
                            unsigned short* __restrict__ dN, unsigned short* __restrict__ wN) {
  const int r = blockIdx.x;       // 0..MP-1
  const int b = blockIdx.y;       // batch
  const int which = blockIdx.z;   // 0=DESC 1=warp_DESC
  const float* src = which ? win : din;
  unsigned short* dst = which ? wN : dN;
  const int t = threadIdx.x;      // 0..255 == channel
  const size_t oo = ((size_t)b * MP + r) * DD + t;
  if (r >= NPTS) { dst[oo] = 0; return; }   // uniform branch per block
  const float v = src[((size_t)b * NPTS + r) * DD + t];
  float s = v * v;
#pragma unroll
  for (int o = 32; o; o >>= 1) s += __shfl_xor(s, o, 64);
  __shared__ float red[4];
  if ((t & 63) == 0) red[t >> 6] = s;
  __syncthreads();
  const float tot = red[0] + red[1] + red[2] + red[3];
  const float scale = 1.f / fmaxf(sqrtf(tot), 1e-12f);
  dst[oo] = f2bf(v * scale);
}

// ---------------- valid[b,kl] = prod over 8x8 block; normsum[b] += valid ----
__global__ void valid_kernel(const float* __restrict__ vmask, float* __restrict__ valid,
                             float* __restrict__ normsum) {
  int gid = blockIdx.x * 256 + threadIdx.x;
  int cell = gid >> 5;   // 32 threads per (b,kl) cell
  int tt = gid & 31;
  if (cell >= NB * NPTS) return;
  int b = cell / NPTS, kl = cell % NPTS;
  int k = kl / WC, l = kl % WC;
  const float* base = vmask + (size_t)b * (NPTS * 64) + (size_t)(k * 8) * (WC * 8) + l * 8;
  int e = tt * 2;
  float p = base[(e >> 3) * (WC * 8) + (e & 7)] * base[((e + 1) >> 3) * (WC * 8) + ((e + 1) & 7)];
#pragma unroll
  for (int o = 16; o; o >>= 1) p *= __shfl_xor(p, o, 32);
  if (tt == 0) { valid[cell] = p; atomicAdd(&normsum[b], p); }
}

// ---------------- bf16 MFMA GEMM: dot = relu(descN . warpN^T) ---------------
// 128x128 tile, BK=64, 4 waves (each 64x64), global_load_lds(16B) with
// XOR-swizzled SOURCE + matching XOR on ds_read (rule #21: both-sides
// involution, linear LDS dest). Fused row sum-of-squares -> R2 atomics.
__global__ __launch_bounds__(256, 2)
void gemm_kernel(const unsigned short* __restrict__ A,
                 const unsigned short* __restrict__ Bm,
                 unsigned short* __restrict__ dot, float* __restrict__ R2) {
  __shared__ unsigned short As[128 * 64];
  __shared__ unsigned short Bs[128 * 64];
  const int bi = blockIdx.x;   // col tile (warp rows)
  const int bj = blockIdx.y;   // row tile (desc rows)
  const int b  = blockIdx.z;
  const int t = threadIdx.x;
  const int lane = t & 63;
  const int w = t >> 6;          // wave 0..3
  const int wr = w >> 1, wc = w & 1;
  const int ls = lane >> 3;          // row-within-8 for staging
  const int swz = (lane & 7) ^ ls;   // pre-swizzled global 16B slot
  const int l15 = lane & 15, g4 = lane >> 4;

  const unsigned short* Ab = A + ((size_t)b * MP + (size_t)bj * 128) * DD;
  const unsigned short* Bb = Bm + ((size_t)b * MP + (size_t)bi * 128) * DD;

  f32x4 acc[4][4] = {};

  for (int k0 = 0; k0 < DD; k0 += 64) {
#pragma unroll
    for (int s = 0; s < 4; ++s) {
      int row = w * 8 + s * 32 + ls;
      const unsigned short* gA = Ab + row * DD + k0 + swz * 8;
      const unsigned short* gB = Bb + row * DD + k0 + swz * 8;
      __builtin_amdgcn_global_load_lds(
          (__attribute__((address_space(1))) unsigned int*)(size_t)gA,
          (__attribute__((address_space(3))) unsigned int*)((char*)As + w * 1024 + s * 4096),
          16, 0, 0);
      __builtin_amdgcn_global_load_lds(
          (__attribute__((address_space(1))) unsigned int*)(size_t)gB,
          (__attribute__((address_space(3))) unsigned int*)((char*)Bs + w * 1024 + s * 4096),
          16, 0, 0);
    }
    __syncthreads();
#pragma unroll
    for (int kk = 0; kk < 2; ++kk) {
      short8 af[4], bfr[4];
#pragma unroll
      for (int m = 0; m < 4; ++m) {
        int row = wr * 64 + m * 16 + l15;
        int colb = (kk * 64 + g4 * 16) ^ ((row & 7) << 4);
        af[m] = *(const short8*)((const char*)As + row * 128 + colb);
      }
#pragma unroll
      for (int n = 0; n < 4; ++n) {
        int row = wc * 64 + n * 16 + l15;
        int colb = (kk * 64 + g4 * 16) ^ ((row & 7) << 4);
        bfr[n] = *(const short8*)((const char*)Bs + row * 128 + colb);
      }
#pragma unroll
      for (int m = 0; m < 4; ++m)
#pragma unroll
        for (int n = 0; n < 4; ++n)
          acc[m][n] = __builtin_amdgcn_mfma_f32_16x16x32_bf16(
              __builtin_bit_cast(bf16x8, af[m]),
              __builtin_bit_cast(bf16x8, bfr[n]),
              acc[m][n], 0, 0, 0);
    }
    __syncthreads();
  }

  // epilogue: relu -> bf16 store + fused row sum-of-squares
#pragma unroll
  for (int m = 0; m < 4; ++m) {
#pragma unroll
    for (int r = 0; r < 4; ++r) {
      const int grow = bj * 128 + wr * 64 + m * 16 + g4 * 4 + r;
      const size_t base = ((size_t)b * NPTS + grow) * NPTS;
      float rs = 0.f;
#pragma unroll
      for (int n = 0; n < 4; ++n) {
        const float v = fmaxf(acc[m][n][r], 0.f);
        rs += v * v;
        const int gcol = bi * 128 + wc * 64 + n * 16 + l15;
        if (grow < NPTS && gcol < NPTS) dot[base + gcol] = f2bf(v);
      }
#pragma unroll
      for (int o = 1; o < 16; o <<= 1) rs += __shfl_xor(rs, o, 64);
      if (l15 == 0 && grow < NPTS)
        atomicAdd(&R2[(size_t)b * NPTS + grow], rs);
    }
  }
}

// ---------------- R2 -> invR in place ---------------------------------------
__global__ void invr_kernel(float* __restrict__ R2) {
  int i = blockIdx.x * 256 + threadIdx.x;
  if (i < NB * NPTS) R2[i] = 1.f / fmaxf(sqrtf(R2[i]), 1e-12f);
}

// ---------------- column sum-of-squares of (dot*invR) -> C2 -----------------
// 2 columns/thread via u32 bf16-pair loads (4 B/lane coalescing).
__global__ void colsum_kernel(const unsigned short* __restrict__ dot,
                              const float* __restrict__ invR, float* __restrict__ C2) {
  const int p = blockIdx.x * 256 + threadIdx.x;   // column pair 0..2399
  if (p >= NPTS / 2) return;
  const int rc = blockIdx.y, b = blockIdx.z;
  const int r0 = rc * 60;
  float s0 = 0.f, s1 = 0.f;
  for (int r = r0; r < r0 + 60; ++r) {
    const size_t ro = (size_t)b * NPTS + r;
    const unsigned u = *(const unsigned*)(dot + ro * NPTS + p * 2);
    const float ir = invR[ro];
    const float f0 = __builtin_bit_cast(float, u << 16) * ir;
    const float f1 = __builtin_bit_cast(float, u & 0xffff0000u) * ir;
    s0 += f0 * f0; s1 += f1 * f1;
  }
  atomicAdd(&C2[b * NPTS + p * 2], s0);
  atomicAdd(&C2[b * NPTS + p * 2 + 1], s1);
}

// ---------------- loss reduce (2 columns/thread) ----------------------------
__global__ void loss_kernel(const unsigned short* __restrict__ dot,
                            const float* __restrict__ invR, const float* __restrict__ C2,
                            const float* __restrict__ valid, const float* __restrict__ normsum,
                            const float* __restrict__ wc, float* __restrict__ out) {
  const int t = threadIdx.x;
  const int p = blockIdx.x * 256 + t;
  const int rc = blockIdx.y, b = blockIdx.z;
  float acc = 0.f;
  if (p < NPTS / 2) {
    const int c0 = p * 2;
    const float invC0 = 1.f / fmaxf(sqrtf(C2[b * NPTS + c0]), 1e-12f);
    const float invC1 = 1.f / fmaxf(sqrtf(C2[b * NPTS + c0 + 1]), 1e-12f);
    // c0 even, WC=80 even -> both columns share the cords row
    const float yk  = (float)(c0 / WC) * 8.f + 4.f;
    const float xl0 = (float)(c0 % WC) * 8.f + 4.f;
    const float xl1 = xl0 + 8.f;
    const int r0 = rc * 60;
    float a0 = 0.f, a1 = 0.f;
    for (int r = r0; r < r0 + 60; ++r) {
      const size_t ro = (size_t)b * NPTS + r;
      const unsigned u = *(const unsigned*)(dot + ro * NPTS + c0);
      const float ir = invR[ro];
      const float d0 = __builtin_bit_cast(float, u << 16) * ir * invC0;
      const float d1 = __builtin_bit_cast(float, u & 0xffff0000u) * ir * invC1;
      const float wy = wc[ro * 2 + 0], wx = wc[ro * 2 + 1];
      const float dy = yk - wy, dx0 = xl0 - wx, dx1 = xl1 - wx;
      const bool S0 = (dy * dy + dx0 * dx0) <= 56.25f;   // dist <= 7.5
      const bool S1 = (dy * dy + dx1 * dx1) <= 56.25f;
      a0 += S0 ? 250.f * fmaxf(0.f, 1.f - d0) : fmaxf(0.f, d0 - 0.2f);
      a1 += S1 ? 250.f * fmaxf(0.f, 1.f - d1) : fmaxf(0.f, d1 - 0.2f);
    }
    acc = (a0 * valid[b * NPTS + c0] + a1 * valid[b * NPTS + c0 + 1])
          / (normsum[b] * (float)NPTS);
  }
#pragma unroll
  for (int o = 32; o; o >>= 1) acc += __shfl_xor(acc, o, 64);
  __shared__ float red[4];
  if ((t & 63) == 0) red[t >> 6] = acc;
  __syncthreads();
  if (t == 0) atomicAdd(out, red[0] + red[1] + red[2] + red[3]);
}

// ---------------------------------------------------------------------------
extern "C" void kernel_launch(void* const* d_in, const int* in_sizes, int n_in,
                              void* d_out, int out_size, void* d_ws, size_t ws_size,
                              hipStream_t stream) {
  (void)in_sizes; (void)n_in; (void)out_size; (void)ws_size;
  const float* DESC  = (const float*)d_in[0];
  const float* WDESC = (const float*)d_in[1];
  const float* HINV  = (const float*)d_in[3];   // H (d_in[2]) is unused by the reference
  const float* VMASK = (const float*)d_in[4];
  float* out = (float*)d_out;

  char* p = (char*)d_ws;
  auto take = [&](size_t bytes) { char* q = p; p += (bytes + 255) & ~(size_t)255; return q; };
  unsigned short* dN   = (unsigned short*)take((size_t)NB * MP * DD * 2);      // ~5.0 MB
  unsigned short* wN   = (unsigned short*)take((size_t)NB * MP * DD * 2);      // ~5.0 MB
  unsigned short* dotb = (unsigned short*)take((size_t)NB * NPTS * NPTS * 2);  // ~92.2 MB
  float* R2      = (float*)take((size_t)NB * NPTS * 4);   // row sumsq -> invR
  float* C2      = (float*)take((size_t)NB * NPTS * 4);
  float* validb  = (float*)take((size_t)NB * NPTS * 4);
  float* wcb     = (float*)take((size_t)NB * NPTS * 8);
  float* normsum = (float*)take(64);

  init_kernel  <<<dim3(38),          dim3(256), 0, stream>>>(C2, R2, normsum, out, HINV, wcb);
  prep_kernel  <<<dim3(MP, NB, 2),   dim3(256), 0, stream>>>(DESC, WDESC, dN, wN);
  valid_kernel <<<dim3(1200),        dim3(256), 0, stream>>>(VMASK, validb, normsum);
  gemm_kernel  <<<dim3(38, 38, NB),  dim3(256), 0, stream>>>(dN, wN, dotb, R2);
  invr_kernel  <<<dim3(38),          dim3(256), 0, stream>>>(R2);
  colsum_kernel<<<dim3(10, 80, NB),  dim3(256), 0, stream>>>(dotb, R2, C2);
  loss_kernel  <<<dim3(10, 80, NB),  dim3(256), 0, stream>>>(dotb, R2, C2, validb, normsum, wcb, out);
}

// Round 10
// 194.393 us; speedup vs baseline: 1.6617x; 1.6617x over previous
//
#include <hip/hip_runtime.h>

#define HC 60
#define WC 80
#define NPTS 4800        // HC*WC
#define DD 256
#define MP 4864          // rows padded to 38*128
#define NB 2
#define NPART 1600       // loss partials: grid 10*80*NB

typedef __attribute__((ext_vector_type(8))) short short8;
typedef __attribute__((ext_vector_type(4))) float f32x4;
typedef __bf16 bf16x8 __attribute__((ext_vector_type(8)));

__device__ __forceinline__ float bf2f(unsigned short u) {
  unsigned x = ((unsigned)u) << 16;
  return __builtin_bit_cast(float, x);
}
__device__ __forceinline__ unsigned short f2bf(float f) {
  unsigned u = __builtin_bit_cast(unsigned, f);
  u += 0x7fffu + ((u >> 16) & 1u);
  return (unsigned short)(u >> 16);
}

// ------- init: zero accumulators + warped coordinates (fused, 38x256) -------
__global__ void init_kernel(float* __restrict__ C2, float* __restrict__ R2,
                            float* __restrict__ normsum, float* __restrict__ out,
                            const float* __restrict__ Hinv, float* __restrict__ wc) {
  int idx = blockIdx.x * 256 + threadIdx.x;
  if (idx < NB) normsum[idx] = 0.f;
  if (idx == 0) out[0] = 0.f;
  if (idx >= NB * NPTS) return;
  C2[idx] = 0.f; R2[idx] = 0.f;
  int b = idx / NPTS, r = idx % NPTS;
  int i = r / WC, j = r % WC;
  float y = i * 8.f + 4.f, x = j * 8.f + 4.f;
  const float* h = Hinv + b * 9;
  float q0 = h[0] * x + h[1] * y + h[2];
  float q1 = h[3] * x + h[4] * y + h[5];
  float z  = h[6] * x + h[7] * y + h[8];
  if (fabsf(z) <= 1e-8f) z = 1e-8f;
  wc[idx * 2 + 0] = q1 / z;   // wy
  wc[idx * 2 + 1] = q0 / z;   // wx
}

// ---------------- per-row l2-normalize + bf16 cast (pad rows -> 0) ----------
__global__ void prep_kernel(const float* __restrict__ din, const float* __restrict__ win,
                            unsigned short* __restrict__ dN, unsigned short* __restrict__ wN) {
  const int r = blockIdx.x;       // 0..MP-1
  const int b = blockIdx.y;       // batch
  const int which = blockIdx.z;   // 0=DESC 1=warp_DESC
  const float* src = which ? win : din;
  unsigned short* dst = which ? wN : dN;
  const int t = threadIdx.x;      // 0..255 == channel
  const size_t oo = ((size_t)b * MP + r) * DD + t;
  if (r >= NPTS) { dst[oo] = 0; return; }   // uniform branch per block
  const float v = src[((size_t)b * NPTS + r) * DD + t];
  float s = v * v;
#pragma unroll
  for (int o = 32; o; o >>= 1) s += __shfl_xor(s, o, 64);
  __shared__ float red[4];
  if ((t & 63) == 0) red[t >> 6] = s;
  __syncthreads();
  const float tot = red[0] + red[1] + red[2] + red[3];
  const float scale = 1.f / fmaxf(sqrtf(tot), 1e-12f);
  dst[oo] = f2bf(v * scale);
}

// ---- valid[b,kl] = prod over 8x8 block (NO atomics — see invr_kernel) ------
__global__ void valid_kernel(const float* __restrict__ vmask, float* __restrict__ valid) {
  int gid = blockIdx.x * 256 + threadIdx.x;
  int cell = gid >> 5;   // 32 threads per (b,kl) cell
  int tt = gid & 31;
  if (cell >= NB * NPTS) return;
  int b = cell / NPTS, kl = cell % NPTS;
  int k = kl / WC, l = kl % WC;
  const float* base = vmask + (size_t)b * (NPTS * 64) + (size_t)(k * 8) * (WC * 8) + l * 8;
  int e = tt * 2;
  float p = base[(e >> 3) * (WC * 8) + (e & 7)] * base[((e + 1) >> 3) * (WC * 8) + ((e + 1) & 7)];
#pragma unroll
  for (int o = 16; o; o >>= 1) p *= __shfl_xor(p, o, 32);
  if (tt == 0) valid[cell] = p;
}

// ---------------- bf16 MFMA GEMM: dot = relu(descN . warpN^T) ---------------
// 128x128 tile, BK=64, 4 waves (each 64x64), global_load_lds(16B) with
// XOR-swizzled SOURCE + matching XOR on ds_read (rule #21: both-sides
// involution, linear LDS dest). Fused row sum-of-squares -> R2 atomics.
__global__ __launch_bounds__(256, 2)
void gemm_kernel(const unsigned short* __restrict__ A,
                 const unsigned short* __restrict__ Bm,
                 unsigned short* __restrict__ dot, float* __restrict__ R2) {
  __shared__ unsigned short As[128 * 64];
  __shared__ unsigned short Bs[128 * 64];
  const int bi = blockIdx.x;   // col tile (warp rows)
  const int bj = blockIdx.y;   // row tile (desc rows)
  const int b  = blockIdx.z;
  const int t = threadIdx.x;
  const int lane = t & 63;
  const int w = t >> 6;          // wave 0..3
  const int wr = w >> 1, wc = w & 1;
  const int ls = lane >> 3;          // row-within-8 for staging
  const int swz = (lane & 7) ^ ls;   // pre-swizzled global 16B slot
  const int l15 = lane & 15, g4 = lane >> 4;

  const unsigned short* Ab = A + ((size_t)b * MP + (size_t)bj * 128) * DD;
  const unsigned short* Bb = Bm + ((size_t)b * MP + (size_t)bi * 128) * DD;

  f32x4 acc[4][4] = {};

  for (int k0 = 0; k0 < DD; k0 += 64) {
#pragma unroll
    for (int s = 0; s < 4; ++s) {
      int row = w * 8 + s * 32 + ls;
      const unsigned short* gA = Ab + row * DD + k0 + swz * 8;
      const unsigned short* gB = Bb + row * DD + k0 + swz * 8;
      __builtin_amdgcn_global_load_lds(
          (__attribute__((address_space(1))) unsigned int*)(size_t)gA,
          (__attribute__((address_space(3))) unsigned int*)((char*)As + w * 1024 + s * 4096),
          16, 0, 0);
      __builtin_amdgcn_global_load_lds(
          (__attribute__((address_space(1))) unsigned int*)(size_t)gB,
          (__attribute__((address_space(3))) unsigned int*)((char*)Bs + w * 1024 + s * 4096),
          16, 0, 0);
    }
    __syncthreads();
#pragma unroll
    for (int kk = 0; kk < 2; ++kk) {
      short8 af[4], bfr[4];
#pragma unroll
      for (int m = 0; m < 4; ++m) {
        int row = wr * 64 + m * 16 + l15;
        int colb = (kk * 64 + g4 * 16) ^ ((row & 7) << 4);
        af[m] = *(const short8*)((const char*)As + row * 128 + colb);
      }
#pragma unroll
      for (int n = 0; n < 4; ++n) {
        int row = wc * 64 + n * 16 + l15;
        int colb = (kk * 64 + g4 * 16) ^ ((row & 7) << 4);
        bfr[n] = *(const short8*)((const char*)Bs + row * 128 + colb);
      }
#pragma unroll
      for (int m = 0; m < 4; ++m)
#pragma unroll
        for (int n = 0; n < 4; ++n)
          acc[m][n] = __builtin_amdgcn_mfma_f32_16x16x32_bf16(
              __builtin_bit_cast(bf16x8, af[m]),
              __builtin_bit_cast(bf16x8, bfr[n]),
              acc[m][n], 0, 0, 0);
    }
    __syncthreads();
  }

  // epilogue: relu -> bf16 store + fused row sum-of-squares
#pragma unroll
  for (int m = 0; m < 4; ++m) {
#pragma unroll
    for (int r = 0; r < 4; ++r) {
      const int grow = bj * 128 + wr * 64 + m * 16 + g4 * 4 + r;
      const size_t base = ((size_t)b * NPTS + grow) * NPTS;
      float rs = 0.f;
#pragma unroll
      for (int n = 0; n < 4; ++n) {
        const float v = fmaxf(acc[m][n][r], 0.f);
        rs += v * v;
        const int gcol = bi * 128 + wc * 64 + n * 16 + l15;
        if (grow < NPTS && gcol < NPTS) dot[base + gcol] = f2bf(v);
      }
#pragma unroll
      for (int o = 1; o < 16; o <<= 1) rs += __shfl_xor(rs, o, 64);
      if (l15 == 0 && grow < NPTS)
        atomicAdd(&R2[(size_t)b * NPTS + grow], rs);
    }
  }
}

// ------- R2 -> invR in place + normsum[b] = sum(valid[b,:]) (76 atomics) ----
__global__ void invr_kernel(float* __restrict__ R2, const float* __restrict__ valid,
                            float* __restrict__ normsum) {
  const int t = threadIdx.x;
  const int i = blockIdx.x * 256 + t;
  float v0 = 0.f, v1 = 0.f;
  if (i < NB * NPTS) {
    R2[i] = 1.f / fmaxf(sqrtf(R2[i]), 1e-12f);
    const float v = valid[i];
    if (i < NPTS) v0 = v; else v1 = v;   // block 18 straddles the batch split
  }
#pragma unroll
  for (int o = 32; o; o >>= 1) { v0 += __shfl_xor(v0, o, 64); v1 += __shfl_xor(v1, o, 64); }
  __shared__ float r0[4], r1[4];
  if ((t & 63) == 0) { r0[t >> 6] = v0; r1[t >> 6] = v1; }
  __syncthreads();
  if (t == 0) {
    const float s0 = r0[0] + r0[1] + r0[2] + r0[3];
    const float s1 = r1[0] + r1[1] + r1[2] + r1[3];
    if (s0 != 0.f) atomicAdd(&normsum[0], s0);
    if (s1 != 0.f) atomicAdd(&normsum[1], s1);
  }
}

// ---------------- column sum-of-squares of (dot*invR) -> C2 -----------------
// 2 columns/thread via u32 bf16-pair loads (4 B/lane coalescing).
__global__ void colsum_kernel(const unsigned short* __restrict__ dot,
                              const float* __restrict__ invR, float* __restrict__ C2) {
  const int p = blockIdx.x * 256 + threadIdx.x;   // column pair 0..2399
  if (p >= NPTS / 2) return;
  const int rc = blockIdx.y, b = blockIdx.z;
  const int r0 = rc * 60;
  float s0 = 0.f, s1 = 0.f;
  for (int r = r0; r < r0 + 60; ++r) {
    const size_t ro = (size_t)b * NPTS + r;
    const unsigned u = *(const unsigned*)(dot + ro * NPTS + p * 2);
    const float ir = invR[ro];
    const float f0 = __builtin_bit_cast(float, u << 16) * ir;
    const float f1 = __builtin_bit_cast(float, u & 0xffff0000u) * ir;
    s0 += f0 * f0; s1 += f1 * f1;
  }
  atomicAdd(&C2[b * NPTS + p * 2], s0);
  atomicAdd(&C2[b * NPTS + p * 2 + 1], s1);
}

// -------- loss reduce (2 columns/thread) -> per-block partials --------------
// No same-address atomics: 1600 contention-free partial stores (round-8 profile
// measured ~26 ns/serialized same-address float atomic; 1600 on out[0] would
// have been atomic-bound at ~42 us vs ~15 us of memory traffic).
__global__ void loss_kernel(const unsigned short* __restrict__ dot,
                            const float* __restrict__ invR, const float* __restrict__ C2,
                            const float* __restrict__ valid, const float* __restrict__ normsum,
                            const float* __restrict__ wc, float* __restrict__ partial) {
  const int t = threadIdx.x;
  const int p = blockIdx.x * 256 + t;
  const int rc = blockIdx.y, b = blockIdx.z;
  float acc = 0.f;
  if (p < NPTS / 2) {
    const int c0 = p * 2;
    const float invC0 = 1.f / fmaxf(sqrtf(C2[b * NPTS + c0]), 1e-12f);
    const float invC1 = 1.f / fmaxf(sqrtf(C2[b * NPTS + c0 + 1]), 1e-12f);
    // c0 even, WC=80 even -> both columns share the cords row
    const float yk  = (float)(c0 / WC) * 8.f + 4.f;
    const float xl0 = (float)(c0 % WC) * 8.f + 4.f;
    const float xl1 = xl0 + 8.f;
    const int r0 = rc * 60;
    float a0 = 0.f, a1 = 0.f;
    for (int r = r0; r < r0 + 60; ++r) {
      const size_t ro = (size_t)b * NPTS + r;
      const unsigned u = *(const unsigned*)(dot + ro * NPTS + c0);
      const float ir = invR[ro];
      const float d0 = __builtin_bit_cast(float, u << 16) * ir * invC0;
      const float d1 = __builtin_bit_cast(float, u & 0xffff0000u) * ir * invC1;
      const float wy = wc[ro * 2 + 0], wx = wc[ro * 2 + 1];
      const float dy = yk - wy, dx0 = xl0 - wx, dx1 = xl1 - wx;
      const bool S0 = (dy * dy + dx0 * dx0) <= 56.25f;   // dist <= 7.5
      const bool S1 = (dy * dy + dx1 * dx1) <= 56.25f;
      a0 += S0 ? 250.f * fmaxf(0.f, 1.f - d0) : fmaxf(0.f, d0 - 0.2f);
      a1 += S1 ? 250.f * fmaxf(0.f, 1.f - d1) : fmaxf(0.f, d1 - 0.2f);
    }
    acc = (a0 * valid[b * NPTS + c0] + a1 * valid[b * NPTS + c0 + 1])
          / (normsum[b] * (float)NPTS);
  }
#pragma unroll
  for (int o = 32; o; o >>= 1) acc += __shfl_xor(acc, o, 64);
  __shared__ float red[4];
  if ((t & 63) == 0) red[t >> 6] = acc;
  __syncthreads();
  if (t == 0)
    partial[blockIdx.x + 10 * (blockIdx.y + 80 * blockIdx.z)] =
        red[0] + red[1] + red[2] + red[3];
}

// ---------------- final: sum 1600 partials -> out[0] (overwrite) ------------
__global__ void final_kernel(const float* __restrict__ partial, float* __restrict__ out) {
  const int t = threadIdx.x;
  float s = 0.f;
  for (int i = t; i < NPART; i += 256) s += partial[i];
#pragma unroll
  for (int o = 32; o; o >>= 1) s += __shfl_xor(s, o, 64);
  __shared__ float red[4];
  if ((t & 63) == 0) red[t >> 6] = s;
  __syncthreads();
  if (t == 0) out[0] = red[0] + red[1] + red[2] + red[3];
}

// ---------------------------------------------------------------------------
extern "C" void kernel_launch(void* const* d_in, const int* in_sizes, int n_in,
                              void* d_out, int out_size, void* d_ws, size_t ws_size,
                              hipStream_t stream) {
  (void)in_sizes; (void)n_in; (void)out_size; (void)ws_size;
  const float* DESC  = (const float*)d_in[0];
  const float* WDESC = (const float*)d_in[1];
  const float* HINV  = (const float*)d_in[3];   // H (d_in[2]) is unused by the reference
  const float* VMASK = (const float*)d_in[4];
  float* out = (float*)d_out;

  char* p = (char*)d_ws;
  auto take = [&](size_t bytes) { char* q = p; p += (bytes + 255) & ~(size_t)255; return q; };
  unsigned short* dN   = (unsigned short*)take((size_t)NB * MP * DD * 2);      // ~5.0 MB
  unsigned short* wN   = (unsigned short*)take((size_t)NB * MP * DD * 2);      // ~5.0 MB
  unsigned short* dotb = (unsigned short*)take((size_t)NB * NPTS * NPTS * 2);  // ~92.2 MB
  float* R2      = (float*)take((size_t)NB * NPTS * 4);   // row sumsq -> invR
  float* C2      = (float*)take((size_t)NB * NPTS * 4);
  float* validb  = (float*)take((size_t)NB * NPTS * 4);
  float* wcb     = (float*)take((size_t)NB * NPTS * 8);
  float* normsum = (float*)take(64);
  float* partial = (float*)take((size_t)NPART * 4);

  init_kernel  <<<dim3(38),          dim3(256), 0, stream>>>(C2, R2, normsum, out, HINV, wcb);
  prep_kernel  <<<dim3(MP, NB, 2),   dim3(256), 0, stream>>>(DESC, WDESC, dN, wN);
  valid_kernel <<<dim3(1200),        dim3(256), 0, stream>>>(VMASK, validb);
  gemm_kernel  <<<dim3(38, 38, NB),  dim3(256), 0, stream>>>(dN, wN, dotb, R2);
  invr_kernel  <<<dim3(38),          dim3(256), 0, stream>>>(R2, validb, normsum);
  colsum_kernel<<<dim3(10, 80, NB),  dim3(256), 0, stream>>>(dotb, R2, C2);
  loss_kernel  <<<dim3(10, 80, NB),  dim3(256), 0, stream>>>(dotb, R2, C2, validb, normsum, wcb, partial);
  final_kernel <<<dim3(1),           dim3(256), 0, stream>>>(partial, out);
}